// Round 7
// baseline (310.280 us; speedup 1.0000x reference)
//
#include <hip/hip_runtime.h>

// N=64 nodes, H=64, M=32, B=16384.
// R4 established: weights converted ONCE per block into LDS fragments (32KB,
// per-lane order -> conflict-free 1KB ds_read_b128), 2 subtiles per fragment
// read. Result 59us, zero bank conflicts, VGPR=128 -- but OccupancyPercent
// 16.8% (2 waves/SIMD) with NO pipe saturated (VALU 52%, LDS ~48%, MFMA 24%)
// == latency-bound on the serial A->pack->B->pack->C chain.
// R5: double occupancy. LDS 33.8KB x 4 = 135KB < 160KB and VGPR 128 = 4
// waves/SIMD now both fit, so: 1024 blocks (64 i x 16 bg, 8 chunks/wave),
// __launch_bounds__(256,4). Per-CU work identical; parallelism 2x.

typedef short bf16x8 __attribute__((ext_vector_type(8)));
typedef float f32x4  __attribute__((ext_vector_type(4)));
typedef unsigned int u32x4 __attribute__((ext_vector_type(4)));

__device__ __forceinline__ unsigned int pack2(float a, float b) {
    // f32->bf16 pair pack, round-to-nearest-ties-away: 2 adds + 1 v_perm (a -> low16)
    union { float f; unsigned int u; } ua, ub; ua.f = a; ub.f = b;
    return __builtin_amdgcn_perm(ub.u + 0x8000u, ua.u + 0x8000u, 0x07060302u);
}

__device__ __forceinline__ f32x4 mfma16(bf16x8 a, bf16x8 b, f32x4 c) {
    return __builtin_amdgcn_mfma_f32_16x16x32_bf16(a, b, c, 0, 0, 0);
}

// pack two relu'd f32x4 D-blocks into one bf16x8 B-operand fragment
__device__ __forceinline__ bf16x8 pack_frag(f32x4 lo, f32x4 hi) {
    union { u32x4 u; bf16x8 v; } r;
    r.u[0] = pack2(fmaxf(lo[0], 0.f), fmaxf(lo[1], 0.f));
    r.u[1] = pack2(fmaxf(lo[2], 0.f), fmaxf(lo[3], 0.f));
    r.u[2] = pack2(fmaxf(hi[0], 0.f), fmaxf(hi[1], 0.f));
    r.u[3] = pack2(fmaxf(hi[2], 0.f), fmaxf(hi[3], 0.f));
    return r.v;
}

// convert 2x f32x4 (possibly non-adjacent) into a bf16x8 A-fragment
__device__ __forceinline__ bf16x8 cvt_frag2(const float* __restrict__ plo,
                                            const float* __restrict__ phi) {
    f32x4 f0 = *(const f32x4*)plo;
    f32x4 f1 = *(const f32x4*)phi;
    union { u32x4 u; bf16x8 v; } r;
    r.u[0] = pack2(f0[0], f0[1]);
    r.u[1] = pack2(f0[2], f0[3]);
    r.u[2] = pack2(f1[0], f1[1]);
    r.u[3] = pack2(f1[2], f1[3]);
    return r.v;
}

__device__ __forceinline__ bf16x8 cvt_frag2_m(const float* __restrict__ plo,
                                              const float* __restrict__ phi,
                                              const unsigned int* M) {
    f32x4 f0 = *(const f32x4*)plo;
    f32x4 f1 = *(const f32x4*)phi;
    union { u32x4 u; bf16x8 v; } r;
    r.u[0] = pack2(f0[0], f0[1]) & M[0];
    r.u[1] = pack2(f0[2], f0[3]) & M[1];
    r.u[2] = pack2(f1[0], f1[1]) & M[2];
    r.u[3] = pack2(f1[2], f1[3]) & M[3];
    return r.v;
}

__global__ __launch_bounds__(256) void prep_x(const float* __restrict__ x,
                                              unsigned short* __restrict__ xb) {
    int j = (blockIdx.x * 256 + threadIdx.x) * 8;
    f32x4 a = *(const f32x4*)&x[j];
    f32x4 b = *(const f32x4*)&x[j + 4];
    u32x4 r = { pack2(a[0], a[1]), pack2(a[2], a[3]), pack2(b[0], b[1]), pack2(b[2], b[3]) };
    *(u32x4*)&xb[j] = r;
}

__global__ __launch_bounds__(256, 4) void main_kernel(
    const float* __restrict__ x,
    const float* __restrict__ W1a, const float* __restrict__ W1b,
    const float* __restrict__ W2a, const float* __restrict__ W2b,
    const float* __restrict__ W3a, const float* __restrict__ b3a,
    const float* __restrict__ W3b, const float* __restrict__ b3b,
    const unsigned short* __restrict__ xb,
    float* __restrict__ out)
{
    const int i    = blockIdx.x & 63;   // same-i blocks 64-strided -> same XCD (weight L2 locality)
    const int bg   = blockIdx.x >> 6;   // 0..15
    const int tid  = threadIdx.x;
    const int w    = tid >> 6;
    const int lane = tid & 63;
    const int q    = lane >> 4;
    const int c0   = lane & 15;

    // 32 fragments x 64 lanes x 16B, per-lane order: read addr = f*1024 + lane*16
    // f: 0-7 A1[t][s], 8-15 A2[t][s], 16-23 A3[t][s], 24-27 F1[t][s], 28-31 F2[t][s]
    __shared__ short lfrag[32 * 512];
    __shared__ float s_vec[3][4][4][4];   // [b3a|w3x|w3b][t][q][r]

    // masks zeroing weight input-column i of W1a/W2a (== masking x column i)
    unsigned int M[2][4];
    {
        const unsigned int halfmask = (i & 1) ? 0x0000FFFFu : 0xFFFF0000u;
        const int dz = (i >> 1) & 3;
        #pragma unroll
        for (int s = 0; s < 2; ++s) {
            bool hit = ((i >> 3) == s * 4 + q);
            #pragma unroll
            for (int d = 0; d < 4; ++d)
                M[s][d] = (hit && d == dz) ? halfmask : 0xFFFFFFFFu;
        }
    }

    // ---- prologue: build all fragments in LDS (each wave owns 8 frag slots) ----
    if (w == 0) {
        const float* p1 = W1a + (i << 12);
        #pragma unroll
        for (int j = 0; j < 8; ++j) {
            int t = j >> 1, s = j & 1;
            int off = (((t << 4) + c0) << 6) + (s << 5) + (q << 3);
            bf16x8 fr = cvt_frag2_m(p1 + off, p1 + off + 4, M[s]);
            *(bf16x8*)&lfrag[j * 512 + lane * 8] = fr;
        }
    } else if (w == 1) {
        const float* p2 = W2a + (i << 12);
        #pragma unroll
        for (int j = 0; j < 8; ++j) {
            int t = j >> 1, s = j & 1;
            int off = (((t << 4) + c0) << 6) + (s << 5) + (q << 3);
            bf16x8 fr = cvt_frag2_m(p2 + off, p2 + off + 4, M[s]);
            *(bf16x8*)&lfrag[(8 + j) * 512 + lane * 8] = fr;
        }
    } else if (w == 2) {
        const float* p3 = W3a + (i << 13);
        #pragma unroll
        for (int j = 0; j < 8; ++j) {
            int t = j >> 1, s = j & 1;
            int base = (((t << 4) + c0) << 7) + (s << 5) + (q << 2);
            bf16x8 fr = cvt_frag2(p3 + base, p3 + base + 16);
            *(bf16x8*)&lfrag[(16 + j) * 512 + lane * 8] = fr;
        }
    } else {
        const float* pb1 = W1b + (i << 11);
        const float* pb2 = W2b + (i << 11);
        #pragma unroll
        for (int j = 0; j < 4; ++j) {
            int t = j >> 1, s = j & 1;
            int base = (((t << 4) + c0) << 6) + (s << 5) + (q << 2);
            bf16x8 fr1 = cvt_frag2(pb1 + base, pb1 + base + 16);
            bf16x8 fr2 = cvt_frag2(pb2 + base, pb2 + base + 16);
            *(bf16x8*)&lfrag[(24 + j) * 512 + lane * 8] = fr1;
            *(bf16x8*)&lfrag[(28 + j) * 512 + lane * 8] = fr2;
        }
    }
    if (tid < 64) {
        int tt = tid >> 4, qq = (tid >> 2) & 3, rr = tid & 3;
        s_vec[0][tt][qq][rr] = b3a[(i << 6) + tid];
        s_vec[2][tt][qq][rr] = W3b[(i << 6) + tid];
        s_vec[1][tt][qq][rr] = W3a[(i << 13) + (tid << 7) + 64 + i];
    }
    const float bb = b3b[i];
    __syncthreads();

    const int wbase = (((bg << 2) + w) << 8);  // 256 rows per wave, 8 chunks of 32

    // preload chunk 0 (2 subtiles of 16 rows)
    bf16x8 XB0[2], XB1[2]; float xd[2];
    #pragma unroll
    for (int r = 0; r < 2; ++r) {
        int rw = wbase + (r << 4) + c0;
        XB0[r] = *(const bf16x8*)&xb[(rw << 6) + (q << 3)];
        XB1[r] = *(const bf16x8*)&xb[(rw << 6) + 32 + (q << 3)];
        xd[r]  = x[(rw << 6) + i];
    }

    for (int k = 0; k < 8; ++k) {
        // prefetch next chunk
        int nb = wbase + ((k < 7 ? k + 1 : 7) << 5) + c0;
        bf16x8 nXB0[2], nXB1[2]; float nxd[2];
        #pragma unroll
        for (int r = 0; r < 2; ++r) {
            int rw = nb + (r << 4);
            nXB0[r] = *(const bf16x8*)&xb[(rw << 6) + (q << 3)];
            nXB1[r] = *(const bf16x8*)&xb[(rw << 6) + 32 + (q << 3)];
            nxd[r]  = x[(rw << 6) + i];
        }

        // ---- phase A: x -> Ha (W1a), x -> Hb (W2a); frag read once, used for both subtiles ----
        f32x4 a1[4][2], a2[4][2];
        #pragma unroll
        for (int t = 0; t < 4; ++t) {
            bf16x8 f10 = *(const bf16x8*)&lfrag[(t * 2 + 0) * 512 + lane * 8];
            bf16x8 f11 = *(const bf16x8*)&lfrag[(t * 2 + 1) * 512 + lane * 8];
            bf16x8 f20 = *(const bf16x8*)&lfrag[(8 + t * 2 + 0) * 512 + lane * 8];
            bf16x8 f21 = *(const bf16x8*)&lfrag[(8 + t * 2 + 1) * 512 + lane * 8];
            #pragma unroll
            for (int r = 0; r < 2; ++r) {
                f32x4 z = {0.f, 0.f, 0.f, 0.f};
                a1[t][r] = mfma16(f11, XB1[r], mfma16(f10, XB0[r], z));
                a2[t][r] = mfma16(f21, XB1[r], mfma16(f20, XB0[r], z));
            }
        }
        bf16x8 HB0[2], HB1[2], GB0[2], GB1[2];
        #pragma unroll
        for (int r = 0; r < 2; ++r) {
            HB0[r] = pack_frag(a1[0][r], a1[1][r]);
            HB1[r] = pack_frag(a1[2][r], a1[3][r]);
            GB0[r] = pack_frag(a2[0][r], a2[1][r]);
            GB1[r] = pack_frag(a2[2][r], a2[3][r]);
        }

        // ---- phase B: Ha -> r1 (W1b), Hb -> r2 (W2b) ----
        f32x4 b1[2][2], b2[2][2];
        #pragma unroll
        for (int t = 0; t < 2; ++t) {
            bf16x8 g10 = *(const bf16x8*)&lfrag[(24 + t * 2 + 0) * 512 + lane * 8];
            bf16x8 g11 = *(const bf16x8*)&lfrag[(24 + t * 2 + 1) * 512 + lane * 8];
            bf16x8 g20 = *(const bf16x8*)&lfrag[(28 + t * 2 + 0) * 512 + lane * 8];
            bf16x8 g21 = *(const bf16x8*)&lfrag[(28 + t * 2 + 1) * 512 + lane * 8];
            #pragma unroll
            for (int r = 0; r < 2; ++r) {
                f32x4 z = {0.f, 0.f, 0.f, 0.f};
                b1[t][r] = mfma16(g11, HB1[r], mfma16(g10, HB0[r], z));
                b2[t][r] = mfma16(g21, GB1[r], mfma16(g20, GB0[r], z));
            }
        }
        bf16x8 RB0[2], RB1[2];
        #pragma unroll
        for (int r = 0; r < 2; ++r) {
            RB0[r] = pack_frag(b1[0][r], b1[1][r]);   // r1 -> A3 s=0 slots
            RB1[r] = pack_frag(b2[0][r], b2[1][r]);   // r2 -> A3 s=1 slots
        }

        // ---- phase C: h = W3a'*[r1;r2] + xd*w3x + b3a; out = relu(dot(relu(h), w3b) + bb) ----
        float p[2] = {0.f, 0.f};
        #pragma unroll
        for (int t = 0; t < 4; ++t) {
            bf16x8 h0 = *(const bf16x8*)&lfrag[(16 + t * 2 + 0) * 512 + lane * 8];
            bf16x8 h1 = *(const bf16x8*)&lfrag[(16 + t * 2 + 1) * 512 + lane * 8];
            f32x4 bv = *(const f32x4*)&s_vec[0][t][q][0];
            f32x4 xv = *(const f32x4*)&s_vec[1][t][q][0];
            f32x4 wv = *(const f32x4*)&s_vec[2][t][q][0];
            #pragma unroll
            for (int r = 0; r < 2; ++r) {
                f32x4 acc;
                #pragma unroll
                for (int e = 0; e < 4; ++e) acc[e] = fmaf(xd[r], xv[e], bv[e]);
                acc = mfma16(h0, RB0[r], acc);
                acc = mfma16(h1, RB1[r], acc);
                #pragma unroll
                for (int e = 0; e < 4; ++e) p[r] = fmaf(fmaxf(acc[e], 0.f), wv[e], p[r]);
            }
        }
        #pragma unroll
        for (int r = 0; r < 2; ++r) {
            float pp = p[r];
            pp += __shfl_xor(pp, 16);
            pp += __shfl_xor(pp, 32);
            int rw = wbase + (k << 5) + (r << 4) + c0;
            if (lane < 16) out[(rw << 6) + i] = fmaxf(pp + bb, 0.f);
        }

        #pragma unroll
        for (int r = 0; r < 2; ++r) { XB0[r] = nXB0[r]; XB1[r] = nXB1[r]; xd[r] = nxd[r]; }
    }
}

extern "C" void kernel_launch(void* const* d_in, const int* in_sizes, int n_in,
                              void* d_out, int out_size, void* d_ws, size_t ws_size,
                              hipStream_t stream) {
    (void)in_sizes; (void)n_in; (void)out_size; (void)ws_size;
    const float* x   = (const float*)d_in[0];
    const float* W1a = (const float*)d_in[1];
    const float* W1b = (const float*)d_in[2];
    const float* W2a = (const float*)d_in[3];
    const float* W2b = (const float*)d_in[4];
    const float* W3a = (const float*)d_in[5];
    const float* b3a = (const float*)d_in[6];
    const float* W3b = (const float*)d_in[7];
    const float* b3b = (const float*)d_in[8];
    float* out = (float*)d_out;
    unsigned short* xb = (unsigned short*)d_ws;

    prep_x<<<512, 256, 0, stream>>>(x, xb);
    main_kernel<<<1024, 256, 0, stream>>>(x, W1a, W1b, W2a, W2b, W3a, b3a, W3b, b3b, xb, out);
}

// Round 8
// 253.084 us; speedup vs baseline: 1.2260x; 1.2260x over previous
//
#include <hip/hip_runtime.h>

// N=64 nodes, H=64, M=32, B=16384.
// R4 established: weights converted ONCE per block into LDS fragments (32KB,
// per-lane order -> conflict-free 1KB ds_read_b128); 59us, zero conflicts,
// VGPR=128, but latency-bound at 2 waves/SIMD (no pipe >52%).
// R5 (launch_bounds(256,4)) hit the spill cliff: budget==demand==128 with
// zero slack -> allocator spilled to VGPR=64, 686MB scratch FETCH, 247us.
// R6: (256,3) -> budget ~170, demand 128 fits with slack. 1024 blocks
// (64 i x 16 bg, 8 chunks/wave) run 3-resident/CU (LDS 3x33.8=101KB<160KB),
// steady-state 12 waves/CU = 1.5x R4 parallelism, same per-CU work.

typedef short bf16x8 __attribute__((ext_vector_type(8)));
typedef float f32x4  __attribute__((ext_vector_type(4)));
typedef unsigned int u32x4 __attribute__((ext_vector_type(4)));

__device__ __forceinline__ unsigned int pack2(float a, float b) {
    // f32->bf16 pair pack, round-to-nearest-ties-away: 2 adds + 1 v_perm (a -> low16)
    union { float f; unsigned int u; } ua, ub; ua.f = a; ub.f = b;
    return __builtin_amdgcn_perm(ub.u + 0x8000u, ua.u + 0x8000u, 0x07060302u);
}

__device__ __forceinline__ f32x4 mfma16(bf16x8 a, bf16x8 b, f32x4 c) {
    return __builtin_amdgcn_mfma_f32_16x16x32_bf16(a, b, c, 0, 0, 0);
}

// pack two relu'd f32x4 D-blocks into one bf16x8 B-operand fragment
__device__ __forceinline__ bf16x8 pack_frag(f32x4 lo, f32x4 hi) {
    union { u32x4 u; bf16x8 v; } r;
    r.u[0] = pack2(fmaxf(lo[0], 0.f), fmaxf(lo[1], 0.f));
    r.u[1] = pack2(fmaxf(lo[2], 0.f), fmaxf(lo[3], 0.f));
    r.u[2] = pack2(fmaxf(hi[0], 0.f), fmaxf(hi[1], 0.f));
    r.u[3] = pack2(fmaxf(hi[2], 0.f), fmaxf(hi[3], 0.f));
    return r.v;
}

// convert 2x f32x4 (possibly non-adjacent) into a bf16x8 A-fragment
__device__ __forceinline__ bf16x8 cvt_frag2(const float* __restrict__ plo,
                                            const float* __restrict__ phi) {
    f32x4 f0 = *(const f32x4*)plo;
    f32x4 f1 = *(const f32x4*)phi;
    union { u32x4 u; bf16x8 v; } r;
    r.u[0] = pack2(f0[0], f0[1]);
    r.u[1] = pack2(f0[2], f0[3]);
    r.u[2] = pack2(f1[0], f1[1]);
    r.u[3] = pack2(f1[2], f1[3]);
    return r.v;
}

__device__ __forceinline__ bf16x8 cvt_frag2_m(const float* __restrict__ plo,
                                              const float* __restrict__ phi,
                                              const unsigned int* M) {
    f32x4 f0 = *(const f32x4*)plo;
    f32x4 f1 = *(const f32x4*)phi;
    union { u32x4 u; bf16x8 v; } r;
    r.u[0] = pack2(f0[0], f0[1]) & M[0];
    r.u[1] = pack2(f0[2], f0[3]) & M[1];
    r.u[2] = pack2(f1[0], f1[1]) & M[2];
    r.u[3] = pack2(f1[2], f1[3]) & M[3];
    return r.v;
}

__global__ __launch_bounds__(256) void prep_x(const float* __restrict__ x,
                                              unsigned short* __restrict__ xb) {
    int j = (blockIdx.x * 256 + threadIdx.x) * 8;
    f32x4 a = *(const f32x4*)&x[j];
    f32x4 b = *(const f32x4*)&x[j + 4];
    u32x4 r = { pack2(a[0], a[1]), pack2(a[2], a[3]), pack2(b[0], b[1]), pack2(b[2], b[3]) };
    *(u32x4*)&xb[j] = r;
}

__global__ __launch_bounds__(256, 3) void main_kernel(
    const float* __restrict__ x,
    const float* __restrict__ W1a, const float* __restrict__ W1b,
    const float* __restrict__ W2a, const float* __restrict__ W2b,
    const float* __restrict__ W3a, const float* __restrict__ b3a,
    const float* __restrict__ W3b, const float* __restrict__ b3b,
    const unsigned short* __restrict__ xb,
    float* __restrict__ out)
{
    const int i    = blockIdx.x & 63;   // same-i blocks 64-strided -> same XCD (weight L2 locality)
    const int bg   = blockIdx.x >> 6;   // 0..15
    const int tid  = threadIdx.x;
    const int w    = tid >> 6;
    const int lane = tid & 63;
    const int q    = lane >> 4;
    const int c0   = lane & 15;

    // 32 fragments x 64 lanes x 16B, per-lane order: read addr = f*1024 + lane*16
    // f: 0-7 A1[t][s], 8-15 A2[t][s], 16-23 A3[t][s], 24-27 F1[t][s], 28-31 F2[t][s]
    __shared__ short lfrag[32 * 512];
    __shared__ float s_vec[3][4][4][4];   // [b3a|w3x|w3b][t][q][r]

    // masks zeroing weight input-column i of W1a/W2a (== masking x column i)
    unsigned int M[2][4];
    {
        const unsigned int halfmask = (i & 1) ? 0x0000FFFFu : 0xFFFF0000u;
        const int dz = (i >> 1) & 3;
        #pragma unroll
        for (int s = 0; s < 2; ++s) {
            bool hit = ((i >> 3) == s * 4 + q);
            #pragma unroll
            for (int d = 0; d < 4; ++d)
                M[s][d] = (hit && d == dz) ? halfmask : 0xFFFFFFFFu;
        }
    }

    // ---- prologue: build all fragments in LDS (each wave owns 8 frag slots) ----
    if (w == 0) {
        const float* p1 = W1a + (i << 12);
        #pragma unroll
        for (int j = 0; j < 8; ++j) {
            int t = j >> 1, s = j & 1;
            int off = (((t << 4) + c0) << 6) + (s << 5) + (q << 3);
            bf16x8 fr = cvt_frag2_m(p1 + off, p1 + off + 4, M[s]);
            *(bf16x8*)&lfrag[j * 512 + lane * 8] = fr;
        }
    } else if (w == 1) {
        const float* p2 = W2a + (i << 12);
        #pragma unroll
        for (int j = 0; j < 8; ++j) {
            int t = j >> 1, s = j & 1;
            int off = (((t << 4) + c0) << 6) + (s << 5) + (q << 3);
            bf16x8 fr = cvt_frag2_m(p2 + off, p2 + off + 4, M[s]);
            *(bf16x8*)&lfrag[(8 + j) * 512 + lane * 8] = fr;
        }
    } else if (w == 2) {
        const float* p3 = W3a + (i << 13);
        #pragma unroll
        for (int j = 0; j < 8; ++j) {
            int t = j >> 1, s = j & 1;
            int base = (((t << 4) + c0) << 7) + (s << 5) + (q << 2);
            bf16x8 fr = cvt_frag2(p3 + base, p3 + base + 16);
            *(bf16x8*)&lfrag[(16 + j) * 512 + lane * 8] = fr;
        }
    } else {
        const float* pb1 = W1b + (i << 11);
        const float* pb2 = W2b + (i << 11);
        #pragma unroll
        for (int j = 0; j < 4; ++j) {
            int t = j >> 1, s = j & 1;
            int base = (((t << 4) + c0) << 6) + (s << 5) + (q << 2);
            bf16x8 fr1 = cvt_frag2(pb1 + base, pb1 + base + 16);
            bf16x8 fr2 = cvt_frag2(pb2 + base, pb2 + base + 16);
            *(bf16x8*)&lfrag[(24 + j) * 512 + lane * 8] = fr1;
            *(bf16x8*)&lfrag[(28 + j) * 512 + lane * 8] = fr2;
        }
    }
    if (tid < 64) {
        int tt = tid >> 4, qq = (tid >> 2) & 3, rr = tid & 3;
        s_vec[0][tt][qq][rr] = b3a[(i << 6) + tid];
        s_vec[2][tt][qq][rr] = W3b[(i << 6) + tid];
        s_vec[1][tt][qq][rr] = W3a[(i << 13) + (tid << 7) + 64 + i];
    }
    const float bb = b3b[i];
    __syncthreads();

    const int wbase = (((bg << 2) + w) << 8);  // 256 rows per wave, 8 chunks of 32

    // preload chunk 0 (2 subtiles of 16 rows)
    bf16x8 XB0[2], XB1[2]; float xd[2];
    #pragma unroll
    for (int r = 0; r < 2; ++r) {
        int rw = wbase + (r << 4) + c0;
        XB0[r] = *(const bf16x8*)&xb[(rw << 6) + (q << 3)];
        XB1[r] = *(const bf16x8*)&xb[(rw << 6) + 32 + (q << 3)];
        xd[r]  = x[(rw << 6) + i];
    }

    for (int k = 0; k < 8; ++k) {
        // prefetch next chunk
        int nb = wbase + ((k < 7 ? k + 1 : 7) << 5) + c0;
        bf16x8 nXB0[2], nXB1[2]; float nxd[2];
        #pragma unroll
        for (int r = 0; r < 2; ++r) {
            int rw = nb + (r << 4);
            nXB0[r] = *(const bf16x8*)&xb[(rw << 6) + (q << 3)];
            nXB1[r] = *(const bf16x8*)&xb[(rw << 6) + 32 + (q << 3)];
            nxd[r]  = x[(rw << 6) + i];
        }

        // ---- phase A: x -> Ha (W1a), x -> Hb (W2a); frag read once, used for both subtiles ----
        f32x4 a1[4][2], a2[4][2];
        #pragma unroll
        for (int t = 0; t < 4; ++t) {
            bf16x8 f10 = *(const bf16x8*)&lfrag[(t * 2 + 0) * 512 + lane * 8];
            bf16x8 f11 = *(const bf16x8*)&lfrag[(t * 2 + 1) * 512 + lane * 8];
            bf16x8 f20 = *(const bf16x8*)&lfrag[(8 + t * 2 + 0) * 512 + lane * 8];
            bf16x8 f21 = *(const bf16x8*)&lfrag[(8 + t * 2 + 1) * 512 + lane * 8];
            #pragma unroll
            for (int r = 0; r < 2; ++r) {
                f32x4 z = {0.f, 0.f, 0.f, 0.f};
                a1[t][r] = mfma16(f11, XB1[r], mfma16(f10, XB0[r], z));
                a2[t][r] = mfma16(f21, XB1[r], mfma16(f20, XB0[r], z));
            }
        }
        bf16x8 HB0[2], HB1[2], GB0[2], GB1[2];
        #pragma unroll
        for (int r = 0; r < 2; ++r) {
            HB0[r] = pack_frag(a1[0][r], a1[1][r]);
            HB1[r] = pack_frag(a1[2][r], a1[3][r]);
            GB0[r] = pack_frag(a2[0][r], a2[1][r]);
            GB1[r] = pack_frag(a2[2][r], a2[3][r]);
        }

        // ---- phase B: Ha -> r1 (W1b), Hb -> r2 (W2b) ----
        f32x4 b1[2][2], b2[2][2];
        #pragma unroll
        for (int t = 0; t < 2; ++t) {
            bf16x8 g10 = *(const bf16x8*)&lfrag[(24 + t * 2 + 0) * 512 + lane * 8];
            bf16x8 g11 = *(const bf16x8*)&lfrag[(24 + t * 2 + 1) * 512 + lane * 8];
            bf16x8 g20 = *(const bf16x8*)&lfrag[(28 + t * 2 + 0) * 512 + lane * 8];
            bf16x8 g21 = *(const bf16x8*)&lfrag[(28 + t * 2 + 1) * 512 + lane * 8];
            #pragma unroll
            for (int r = 0; r < 2; ++r) {
                f32x4 z = {0.f, 0.f, 0.f, 0.f};
                b1[t][r] = mfma16(g11, HB1[r], mfma16(g10, HB0[r], z));
                b2[t][r] = mfma16(g21, GB1[r], mfma16(g20, GB0[r], z));
            }
        }
        bf16x8 RB0[2], RB1[2];
        #pragma unroll
        for (int r = 0; r < 2; ++r) {
            RB0[r] = pack_frag(b1[0][r], b1[1][r]);   // r1 -> A3 s=0 slots
            RB1[r] = pack_frag(b2[0][r], b2[1][r]);   // r2 -> A3 s=1 slots
        }

        // ---- phase C: h = W3a'*[r1;r2] + xd*w3x + b3a; out = relu(dot(relu(h), w3b) + bb) ----
        float p[2] = {0.f, 0.f};
        #pragma unroll
        for (int t = 0; t < 4; ++t) {
            bf16x8 h0 = *(const bf16x8*)&lfrag[(16 + t * 2 + 0) * 512 + lane * 8];
            bf16x8 h1 = *(const bf16x8*)&lfrag[(16 + t * 2 + 1) * 512 + lane * 8];
            f32x4 bv = *(const f32x4*)&s_vec[0][t][q][0];
            f32x4 xv = *(const f32x4*)&s_vec[1][t][q][0];
            f32x4 wv = *(const f32x4*)&s_vec[2][t][q][0];
            #pragma unroll
            for (int r = 0; r < 2; ++r) {
                f32x4 acc;
                #pragma unroll
                for (int e = 0; e < 4; ++e) acc[e] = fmaf(xd[r], xv[e], bv[e]);
                acc = mfma16(h0, RB0[r], acc);
                acc = mfma16(h1, RB1[r], acc);
                #pragma unroll
                for (int e = 0; e < 4; ++e) p[r] = fmaf(fmaxf(acc[e], 0.f), wv[e], p[r]);
            }
        }
        #pragma unroll
        for (int r = 0; r < 2; ++r) {
            float pp = p[r];
            pp += __shfl_xor(pp, 16);
            pp += __shfl_xor(pp, 32);
            int rw = wbase + (k << 5) + (r << 4) + c0;
            if (lane < 16) out[(rw << 6) + i] = fmaxf(pp + bb, 0.f);
        }

        #pragma unroll
        for (int r = 0; r < 2; ++r) { XB0[r] = nXB0[r]; XB1[r] = nXB1[r]; xd[r] = nxd[r]; }
    }
}

extern "C" void kernel_launch(void* const* d_in, const int* in_sizes, int n_in,
                              void* d_out, int out_size, void* d_ws, size_t ws_size,
                              hipStream_t stream) {
    (void)in_sizes; (void)n_in; (void)out_size; (void)ws_size;
    const float* x   = (const float*)d_in[0];
    const float* W1a = (const float*)d_in[1];
    const float* W1b = (const float*)d_in[2];
    const float* W2a = (const float*)d_in[3];
    const float* W2b = (const float*)d_in[4];
    const float* W3a = (const float*)d_in[5];
    const float* b3a = (const float*)d_in[6];
    const float* W3b = (const float*)d_in[7];
    const float* b3b = (const float*)d_in[8];
    float* out = (float*)d_out;
    unsigned short* xb = (unsigned short*)d_ws;

    prep_x<<<512, 256, 0, stream>>>(x, xb);
    main_kernel<<<1024, 256, 0, stream>>>(x, W1a, W1b, W2a, W2b, W3a, b3a, W3b, b3b, xb, out);
}

// Round 9
// 125.054 us; speedup vs baseline: 2.4812x; 2.0238x over previous
//
#include <hip/hip_runtime.h>

// N=64 nodes, H=64, M=32, B=16384.
// R4 established: weights -> LDS fragments once per block (33.8KB, per-lane
// order, conflict-free 1KB ds_read_b128); 59us, VGPR=128, zero spills, but
// grid=512 capped runtime occupancy at 2 blocks/CU (latency-bound, no pipe
// >52%). R5/R6 proved ANY launch_bounds min-waves >= 3 triggers cascade
// spilling (VGPR 64/84, 0.5-0.7GB scratch traffic). R7: keep (256,2) --
// bit-identical codegen to R4 -- and raise the GRID to 1024 blocks
// (64 i x 16 bg, 8 chunks/wave). VGPR=128 allows 4 waves/SIMD and
// LDS 4x33.8=135KB<160KB, so HW co-schedules 4 blocks/CU: 2x parallelism
// with the allocator untouched.

typedef short bf16x8 __attribute__((ext_vector_type(8)));
typedef float f32x4  __attribute__((ext_vector_type(4)));
typedef unsigned int u32x4 __attribute__((ext_vector_type(4)));

__device__ __forceinline__ unsigned int pack2(float a, float b) {
    // f32->bf16 pair pack, round-to-nearest-ties-away: 2 adds + 1 v_perm (a -> low16)
    union { float f; unsigned int u; } ua, ub; ua.f = a; ub.f = b;
    return __builtin_amdgcn_perm(ub.u + 0x8000u, ua.u + 0x8000u, 0x07060302u);
}

__device__ __forceinline__ f32x4 mfma16(bf16x8 a, bf16x8 b, f32x4 c) {
    return __builtin_amdgcn_mfma_f32_16x16x32_bf16(a, b, c, 0, 0, 0);
}

// pack two relu'd f32x4 D-blocks into one bf16x8 B-operand fragment
__device__ __forceinline__ bf16x8 pack_frag(f32x4 lo, f32x4 hi) {
    union { u32x4 u; bf16x8 v; } r;
    r.u[0] = pack2(fmaxf(lo[0], 0.f), fmaxf(lo[1], 0.f));
    r.u[1] = pack2(fmaxf(lo[2], 0.f), fmaxf(lo[3], 0.f));
    r.u[2] = pack2(fmaxf(hi[0], 0.f), fmaxf(hi[1], 0.f));
    r.u[3] = pack2(fmaxf(hi[2], 0.f), fmaxf(hi[3], 0.f));
    return r.v;
}

// convert 2x f32x4 (possibly non-adjacent) into a bf16x8 A-fragment
__device__ __forceinline__ bf16x8 cvt_frag2(const float* __restrict__ plo,
                                            const float* __restrict__ phi) {
    f32x4 f0 = *(const f32x4*)plo;
    f32x4 f1 = *(const f32x4*)phi;
    union { u32x4 u; bf16x8 v; } r;
    r.u[0] = pack2(f0[0], f0[1]);
    r.u[1] = pack2(f0[2], f0[3]);
    r.u[2] = pack2(f1[0], f1[1]);
    r.u[3] = pack2(f1[2], f1[3]);
    return r.v;
}

__device__ __forceinline__ bf16x8 cvt_frag2_m(const float* __restrict__ plo,
                                              const float* __restrict__ phi,
                                              const unsigned int* M) {
    f32x4 f0 = *(const f32x4*)plo;
    f32x4 f1 = *(const f32x4*)phi;
    union { u32x4 u; bf16x8 v; } r;
    r.u[0] = pack2(f0[0], f0[1]) & M[0];
    r.u[1] = pack2(f0[2], f0[3]) & M[1];
    r.u[2] = pack2(f1[0], f1[1]) & M[2];
    r.u[3] = pack2(f1[2], f1[3]) & M[3];
    return r.v;
}

__global__ __launch_bounds__(256) void prep_x(const float* __restrict__ x,
                                              unsigned short* __restrict__ xb) {
    int j = (blockIdx.x * 256 + threadIdx.x) * 8;
    f32x4 a = *(const f32x4*)&x[j];
    f32x4 b = *(const f32x4*)&x[j + 4];
    u32x4 r = { pack2(a[0], a[1]), pack2(a[2], a[3]), pack2(b[0], b[1]), pack2(b[2], b[3]) };
    *(u32x4*)&xb[j] = r;
}

__global__ __launch_bounds__(256, 2) void main_kernel(
    const float* __restrict__ x,
    const float* __restrict__ W1a, const float* __restrict__ W1b,
    const float* __restrict__ W2a, const float* __restrict__ W2b,
    const float* __restrict__ W3a, const float* __restrict__ b3a,
    const float* __restrict__ W3b, const float* __restrict__ b3b,
    const unsigned short* __restrict__ xb,
    float* __restrict__ out)
{
    const int i    = blockIdx.x & 63;   // same-i blocks 64-strided -> same XCD (weight L2 locality)
    const int bg   = blockIdx.x >> 6;   // 0..15
    const int tid  = threadIdx.x;
    const int w    = tid >> 6;
    const int lane = tid & 63;
    const int q    = lane >> 4;
    const int c0   = lane & 15;

    // 32 fragments x 64 lanes x 16B, per-lane order: read addr = f*1024 + lane*16
    // f: 0-7 A1[t][s], 8-15 A2[t][s], 16-23 A3[t][s], 24-27 F1[t][s], 28-31 F2[t][s]
    __shared__ short lfrag[32 * 512];
    __shared__ float s_vec[3][4][4][4];   // [b3a|w3x|w3b][t][q][r]

    // masks zeroing weight input-column i of W1a/W2a (== masking x column i)
    unsigned int M[2][4];
    {
        const unsigned int halfmask = (i & 1) ? 0x0000FFFFu : 0xFFFF0000u;
        const int dz = (i >> 1) & 3;
        #pragma unroll
        for (int s = 0; s < 2; ++s) {
            bool hit = ((i >> 3) == s * 4 + q);
            #pragma unroll
            for (int d = 0; d < 4; ++d)
                M[s][d] = (hit && d == dz) ? halfmask : 0xFFFFFFFFu;
        }
    }

    // ---- prologue: build all fragments in LDS (each wave owns 8 frag slots) ----
    if (w == 0) {
        const float* p1 = W1a + (i << 12);
        #pragma unroll
        for (int j = 0; j < 8; ++j) {
            int t = j >> 1, s = j & 1;
            int off = (((t << 4) + c0) << 6) + (s << 5) + (q << 3);
            bf16x8 fr = cvt_frag2_m(p1 + off, p1 + off + 4, M[s]);
            *(bf16x8*)&lfrag[j * 512 + lane * 8] = fr;
        }
    } else if (w == 1) {
        const float* p2 = W2a + (i << 12);
        #pragma unroll
        for (int j = 0; j < 8; ++j) {
            int t = j >> 1, s = j & 1;
            int off = (((t << 4) + c0) << 6) + (s << 5) + (q << 3);
            bf16x8 fr = cvt_frag2_m(p2 + off, p2 + off + 4, M[s]);
            *(bf16x8*)&lfrag[(8 + j) * 512 + lane * 8] = fr;
        }
    } else if (w == 2) {
        const float* p3 = W3a + (i << 13);
        #pragma unroll
        for (int j = 0; j < 8; ++j) {
            int t = j >> 1, s = j & 1;
            int base = (((t << 4) + c0) << 7) + (s << 5) + (q << 2);
            bf16x8 fr = cvt_frag2(p3 + base, p3 + base + 16);
            *(bf16x8*)&lfrag[(16 + j) * 512 + lane * 8] = fr;
        }
    } else {
        const float* pb1 = W1b + (i << 11);
        const float* pb2 = W2b + (i << 11);
        #pragma unroll
        for (int j = 0; j < 4; ++j) {
            int t = j >> 1, s = j & 1;
            int base = (((t << 4) + c0) << 6) + (s << 5) + (q << 2);
            bf16x8 fr1 = cvt_frag2(pb1 + base, pb1 + base + 16);
            bf16x8 fr2 = cvt_frag2(pb2 + base, pb2 + base + 16);
            *(bf16x8*)&lfrag[(24 + j) * 512 + lane * 8] = fr1;
            *(bf16x8*)&lfrag[(28 + j) * 512 + lane * 8] = fr2;
        }
    }
    if (tid < 64) {
        int tt = tid >> 4, qq = (tid >> 2) & 3, rr = tid & 3;
        s_vec[0][tt][qq][rr] = b3a[(i << 6) + tid];
        s_vec[2][tt][qq][rr] = W3b[(i << 6) + tid];
        s_vec[1][tt][qq][rr] = W3a[(i << 13) + (tid << 7) + 64 + i];
    }
    const float bb = b3b[i];
    __syncthreads();

    const int wbase = (((bg << 2) + w) << 8);  // 256 rows per wave, 8 chunks of 32

    // preload chunk 0 (2 subtiles of 16 rows)
    bf16x8 XB0[2], XB1[2]; float xd[2];
    #pragma unroll
    for (int r = 0; r < 2; ++r) {
        int rw = wbase + (r << 4) + c0;
        XB0[r] = *(const bf16x8*)&xb[(rw << 6) + (q << 3)];
        XB1[r] = *(const bf16x8*)&xb[(rw << 6) + 32 + (q << 3)];
        xd[r]  = x[(rw << 6) + i];
    }

    for (int k = 0; k < 8; ++k) {
        // prefetch next chunk
        int nb = wbase + ((k < 7 ? k + 1 : 7) << 5) + c0;
        bf16x8 nXB0[2], nXB1[2]; float nxd[2];
        #pragma unroll
        for (int r = 0; r < 2; ++r) {
            int rw = nb + (r << 4);
            nXB0[r] = *(const bf16x8*)&xb[(rw << 6) + (q << 3)];
            nXB1[r] = *(const bf16x8*)&xb[(rw << 6) + 32 + (q << 3)];
            nxd[r]  = x[(rw << 6) + i];
        }

        // ---- phase A: x -> Ha (W1a), x -> Hb (W2a); frag read once, used for both subtiles ----
        f32x4 a1[4][2], a2[4][2];
        #pragma unroll
        for (int t = 0; t < 4; ++t) {
            bf16x8 f10 = *(const bf16x8*)&lfrag[(t * 2 + 0) * 512 + lane * 8];
            bf16x8 f11 = *(const bf16x8*)&lfrag[(t * 2 + 1) * 512 + lane * 8];
            bf16x8 f20 = *(const bf16x8*)&lfrag[(8 + t * 2 + 0) * 512 + lane * 8];
            bf16x8 f21 = *(const bf16x8*)&lfrag[(8 + t * 2 + 1) * 512 + lane * 8];
            #pragma unroll
            for (int r = 0; r < 2; ++r) {
                f32x4 z = {0.f, 0.f, 0.f, 0.f};
                a1[t][r] = mfma16(f11, XB1[r], mfma16(f10, XB0[r], z));
                a2[t][r] = mfma16(f21, XB1[r], mfma16(f20, XB0[r], z));
            }
        }
        bf16x8 HB0[2], HB1[2], GB0[2], GB1[2];
        #pragma unroll
        for (int r = 0; r < 2; ++r) {
            HB0[r] = pack_frag(a1[0][r], a1[1][r]);
            HB1[r] = pack_frag(a1[2][r], a1[3][r]);
            GB0[r] = pack_frag(a2[0][r], a2[1][r]);
            GB1[r] = pack_frag(a2[2][r], a2[3][r]);
        }

        // ---- phase B: Ha -> r1 (W1b), Hb -> r2 (W2b) ----
        f32x4 b1[2][2], b2[2][2];
        #pragma unroll
        for (int t = 0; t < 2; ++t) {
            bf16x8 g10 = *(const bf16x8*)&lfrag[(24 + t * 2 + 0) * 512 + lane * 8];
            bf16x8 g11 = *(const bf16x8*)&lfrag[(24 + t * 2 + 1) * 512 + lane * 8];
            bf16x8 g20 = *(const bf16x8*)&lfrag[(28 + t * 2 + 0) * 512 + lane * 8];
            bf16x8 g21 = *(const bf16x8*)&lfrag[(28 + t * 2 + 1) * 512 + lane * 8];
            #pragma unroll
            for (int r = 0; r < 2; ++r) {
                f32x4 z = {0.f, 0.f, 0.f, 0.f};
                b1[t][r] = mfma16(g11, HB1[r], mfma16(g10, HB0[r], z));
                b2[t][r] = mfma16(g21, GB1[r], mfma16(g20, GB0[r], z));
            }
        }
        bf16x8 RB0[2], RB1[2];
        #pragma unroll
        for (int r = 0; r < 2; ++r) {
            RB0[r] = pack_frag(b1[0][r], b1[1][r]);   // r1 -> A3 s=0 slots
            RB1[r] = pack_frag(b2[0][r], b2[1][r]);   // r2 -> A3 s=1 slots
        }

        // ---- phase C: h = W3a'*[r1;r2] + xd*w3x + b3a; out = relu(dot(relu(h), w3b) + bb) ----
        float p[2] = {0.f, 0.f};
        #pragma unroll
        for (int t = 0; t < 4; ++t) {
            bf16x8 h0 = *(const bf16x8*)&lfrag[(16 + t * 2 + 0) * 512 + lane * 8];
            bf16x8 h1 = *(const bf16x8*)&lfrag[(16 + t * 2 + 1) * 512 + lane * 8];
            f32x4 bv = *(const f32x4*)&s_vec[0][t][q][0];
            f32x4 xv = *(const f32x4*)&s_vec[1][t][q][0];
            f32x4 wv = *(const f32x4*)&s_vec[2][t][q][0];
            #pragma unroll
            for (int r = 0; r < 2; ++r) {
                f32x4 acc;
                #pragma unroll
                for (int e = 0; e < 4; ++e) acc[e] = fmaf(xd[r], xv[e], bv[e]);
                acc = mfma16(h0, RB0[r], acc);
                acc = mfma16(h1, RB1[r], acc);
                #pragma unroll
                for (int e = 0; e < 4; ++e) p[r] = fmaf(fmaxf(acc[e], 0.f), wv[e], p[r]);
            }
        }
        #pragma unroll
        for (int r = 0; r < 2; ++r) {
            float pp = p[r];
            pp += __shfl_xor(pp, 16);
            pp += __shfl_xor(pp, 32);
            int rw = wbase + (k << 5) + (r << 4) + c0;
            if (lane < 16) out[(rw << 6) + i] = fmaxf(pp + bb, 0.f);
        }

        #pragma unroll
        for (int r = 0; r < 2; ++r) { XB0[r] = nXB0[r]; XB1[r] = nXB1[r]; xd[r] = nxd[r]; }
    }
}

extern "C" void kernel_launch(void* const* d_in, const int* in_sizes, int n_in,
                              void* d_out, int out_size, void* d_ws, size_t ws_size,
                              hipStream_t stream) {
    (void)in_sizes; (void)n_in; (void)out_size; (void)ws_size;
    const float* x   = (const float*)d_in[0];
    const float* W1a = (const float*)d_in[1];
    const float* W1b = (const float*)d_in[2];
    const float* W2a = (const float*)d_in[3];
    const float* W2b = (const float*)d_in[4];
    const float* W3a = (const float*)d_in[5];
    const float* b3a = (const float*)d_in[6];
    const float* W3b = (const float*)d_in[7];
    const float* b3b = (const float*)d_in[8];
    float* out = (float*)d_out;
    unsigned short* xb = (unsigned short*)d_ws;

    prep_x<<<512, 256, 0, stream>>>(x, xb);
    main_kernel<<<1024, 256, 0, stream>>>(x, W1a, W1b, W2a, W2b, W3a, b3a, W3b, b3b, xb, out);
}

// Round 10
// 119.682 us; speedup vs baseline: 2.5925x; 1.0449x over previous
//
#include <hip/hip_runtime.h>

// N=64 nodes, H=64, M=32, B=16384.
// R4 base: weights -> LDS fragments once per block (33.8KB, per-lane order,
// conflict-free 1KB ds_read_b128), 2 subtiles per fragment read; 59us.
// R5-R7 established: launch_bounds >=3 spills catastrophically; extra grid
// blocks don't raise measured occupancy or perf. Per-CU pipe totals at R4:
// LDS ~28us (44 b128/chunk), VALU ~30us, MFMA ~14us; sum ~= measured 61.5
// -> pipes barely overlap, so reduce TOTALS:
// R8a: pack2 via v_cvt_pk_bf16_f32 (1 VALU/pair vs 3) -> -96 VALU/chunk.
// R8b: hoist phase-A fragments (A1/A2, 16 of 44 b128/chunk) into registers
//      before the k-loop (demand ~192 < 256 budget; worst case compiler
//      sinks the reads back = R4 baseline).

typedef short bf16x8 __attribute__((ext_vector_type(8)));
typedef float f32x4  __attribute__((ext_vector_type(4)));
typedef unsigned int u32x4 __attribute__((ext_vector_type(4)));

__device__ __forceinline__ unsigned int pack2(float a, float b) {
    // f32x2 -> packed bf16x2 in ONE VALU op (RTNE); a -> low16, b -> high16
    unsigned int r;
    asm("v_cvt_pk_bf16_f32 %0, %1, %2" : "=v"(r) : "v"(a), "v"(b));
    return r;
}

__device__ __forceinline__ f32x4 mfma16(bf16x8 a, bf16x8 b, f32x4 c) {
    return __builtin_amdgcn_mfma_f32_16x16x32_bf16(a, b, c, 0, 0, 0);
}

// pack two relu'd f32x4 D-blocks into one bf16x8 B-operand fragment
__device__ __forceinline__ bf16x8 pack_frag(f32x4 lo, f32x4 hi) {
    union { u32x4 u; bf16x8 v; } r;
    r.u[0] = pack2(fmaxf(lo[0], 0.f), fmaxf(lo[1], 0.f));
    r.u[1] = pack2(fmaxf(lo[2], 0.f), fmaxf(lo[3], 0.f));
    r.u[2] = pack2(fmaxf(hi[0], 0.f), fmaxf(hi[1], 0.f));
    r.u[3] = pack2(fmaxf(hi[2], 0.f), fmaxf(hi[3], 0.f));
    return r.v;
}

// convert 2x f32x4 (possibly non-adjacent) into a bf16x8 A-fragment
__device__ __forceinline__ bf16x8 cvt_frag2(const float* __restrict__ plo,
                                            const float* __restrict__ phi) {
    f32x4 f0 = *(const f32x4*)plo;
    f32x4 f1 = *(const f32x4*)phi;
    union { u32x4 u; bf16x8 v; } r;
    r.u[0] = pack2(f0[0], f0[1]);
    r.u[1] = pack2(f0[2], f0[3]);
    r.u[2] = pack2(f1[0], f1[1]);
    r.u[3] = pack2(f1[2], f1[3]);
    return r.v;
}

__device__ __forceinline__ bf16x8 cvt_frag2_m(const float* __restrict__ plo,
                                              const float* __restrict__ phi,
                                              const unsigned int* M) {
    f32x4 f0 = *(const f32x4*)plo;
    f32x4 f1 = *(const f32x4*)phi;
    union { u32x4 u; bf16x8 v; } r;
    r.u[0] = pack2(f0[0], f0[1]) & M[0];
    r.u[1] = pack2(f0[2], f0[3]) & M[1];
    r.u[2] = pack2(f1[0], f1[1]) & M[2];
    r.u[3] = pack2(f1[2], f1[3]) & M[3];
    return r.v;
}

__global__ __launch_bounds__(256) void prep_x(const float* __restrict__ x,
                                              unsigned short* __restrict__ xb) {
    int j = (blockIdx.x * 256 + threadIdx.x) * 8;
    f32x4 a = *(const f32x4*)&x[j];
    f32x4 b = *(const f32x4*)&x[j + 4];
    u32x4 r = { pack2(a[0], a[1]), pack2(a[2], a[3]), pack2(b[0], b[1]), pack2(b[2], b[3]) };
    *(u32x4*)&xb[j] = r;
}

__global__ __launch_bounds__(256, 2) void main_kernel(
    const float* __restrict__ x,
    const float* __restrict__ W1a, const float* __restrict__ W1b,
    const float* __restrict__ W2a, const float* __restrict__ W2b,
    const float* __restrict__ W3a, const float* __restrict__ b3a,
    const float* __restrict__ W3b, const float* __restrict__ b3b,
    const unsigned short* __restrict__ xb,
    float* __restrict__ out)
{
    const int i    = blockIdx.x & 63;   // same-i blocks 64-strided -> same XCD (weight L2 locality)
    const int bg   = blockIdx.x >> 6;   // 0..7
    const int tid  = threadIdx.x;
    const int w    = tid >> 6;
    const int lane = tid & 63;
    const int q    = lane >> 4;
    const int c0   = lane & 15;

    // 32 fragments x 64 lanes x 16B, per-lane order: read addr = f*1024 + lane*16
    // f: 0-7 A1[t][s], 8-15 A2[t][s], 16-23 A3[t][s], 24-27 F1[t][s], 28-31 F2[t][s]
    __shared__ short lfrag[32 * 512];
    __shared__ float s_vec[3][4][4][4];   // [b3a|w3x|w3b][t][q][r]

    // masks zeroing weight input-column i of W1a/W2a (== masking x column i)
    unsigned int M[2][4];
    {
        const unsigned int halfmask = (i & 1) ? 0x0000FFFFu : 0xFFFF0000u;
        const int dz = (i >> 1) & 3;
        #pragma unroll
        for (int s = 0; s < 2; ++s) {
            bool hit = ((i >> 3) == s * 4 + q);
            #pragma unroll
            for (int d = 0; d < 4; ++d)
                M[s][d] = (hit && d == dz) ? halfmask : 0xFFFFFFFFu;
        }
    }

    // ---- prologue: build all fragments in LDS (each wave owns 8 frag slots) ----
    if (w == 0) {
        const float* p1 = W1a + (i << 12);
        #pragma unroll
        for (int j = 0; j < 8; ++j) {
            int t = j >> 1, s = j & 1;
            int off = (((t << 4) + c0) << 6) + (s << 5) + (q << 3);
            bf16x8 fr = cvt_frag2_m(p1 + off, p1 + off + 4, M[s]);
            *(bf16x8*)&lfrag[j * 512 + lane * 8] = fr;
        }
    } else if (w == 1) {
        const float* p2 = W2a + (i << 12);
        #pragma unroll
        for (int j = 0; j < 8; ++j) {
            int t = j >> 1, s = j & 1;
            int off = (((t << 4) + c0) << 6) + (s << 5) + (q << 3);
            bf16x8 fr = cvt_frag2_m(p2 + off, p2 + off + 4, M[s]);
            *(bf16x8*)&lfrag[(8 + j) * 512 + lane * 8] = fr;
        }
    } else if (w == 2) {
        const float* p3 = W3a + (i << 13);
        #pragma unroll
        for (int j = 0; j < 8; ++j) {
            int t = j >> 1, s = j & 1;
            int base = (((t << 4) + c0) << 7) + (s << 5) + (q << 2);
            bf16x8 fr = cvt_frag2(p3 + base, p3 + base + 16);
            *(bf16x8*)&lfrag[(16 + j) * 512 + lane * 8] = fr;
        }
    } else {
        const float* pb1 = W1b + (i << 11);
        const float* pb2 = W2b + (i << 11);
        #pragma unroll
        for (int j = 0; j < 4; ++j) {
            int t = j >> 1, s = j & 1;
            int base = (((t << 4) + c0) << 6) + (s << 5) + (q << 2);
            bf16x8 fr1 = cvt_frag2(pb1 + base, pb1 + base + 16);
            bf16x8 fr2 = cvt_frag2(pb2 + base, pb2 + base + 16);
            *(bf16x8*)&lfrag[(24 + j) * 512 + lane * 8] = fr1;
            *(bf16x8*)&lfrag[(28 + j) * 512 + lane * 8] = fr2;
        }
    }
    if (tid < 64) {
        int tt = tid >> 4, qq = (tid >> 2) & 3, rr = tid & 3;
        s_vec[0][tt][qq][rr] = b3a[(i << 6) + tid];
        s_vec[2][tt][qq][rr] = W3b[(i << 6) + tid];
        s_vec[1][tt][qq][rr] = W3a[(i << 13) + (tid << 7) + 64 + i];
    }
    const float bb = b3b[i];
    __syncthreads();

    // ---- R8b: phase-A fragments live in registers across the whole k-loop.
    // 16 frags = 64 VGPRs; demand ~192 fits the (256,2) budget with slack.
    // Worst case the compiler sinks these ds_reads back into the loop, which
    // is exactly the R4 baseline (no downside).
    bf16x8 A1f[4][2], A2f[4][2];
    #pragma unroll
    for (int t = 0; t < 4; ++t)
        #pragma unroll
        for (int s = 0; s < 2; ++s) {
            A1f[t][s] = *(const bf16x8*)&lfrag[(t * 2 + s) * 512 + lane * 8];
            A2f[t][s] = *(const bf16x8*)&lfrag[(8 + t * 2 + s) * 512 + lane * 8];
        }

    const int wbase = (((bg << 2) + w) << 9);  // 512 rows per wave, 16 chunks of 32

    // preload chunk 0 (2 subtiles of 16 rows)
    bf16x8 XB0[2], XB1[2]; float xd[2];
    #pragma unroll
    for (int r = 0; r < 2; ++r) {
        int rw = wbase + (r << 4) + c0;
        XB0[r] = *(const bf16x8*)&xb[(rw << 6) + (q << 3)];
        XB1[r] = *(const bf16x8*)&xb[(rw << 6) + 32 + (q << 3)];
        xd[r]  = x[(rw << 6) + i];
    }

    for (int k = 0; k < 16; ++k) {
        // prefetch next chunk
        int nb = wbase + ((k < 15 ? k + 1 : 15) << 5) + c0;
        bf16x8 nXB0[2], nXB1[2]; float nxd[2];
        #pragma unroll
        for (int r = 0; r < 2; ++r) {
            int rw = nb + (r << 4);
            nXB0[r] = *(const bf16x8*)&xb[(rw << 6) + (q << 3)];
            nXB1[r] = *(const bf16x8*)&xb[(rw << 6) + 32 + (q << 3)];
            nxd[r]  = x[(rw << 6) + i];
        }

        // ---- phase A: x -> Ha (W1a), x -> Hb (W2a); frags from registers ----
        f32x4 a1[4][2], a2[4][2];
        #pragma unroll
        for (int t = 0; t < 4; ++t) {
            #pragma unroll
            for (int r = 0; r < 2; ++r) {
                f32x4 z = {0.f, 0.f, 0.f, 0.f};
                a1[t][r] = mfma16(A1f[t][1], XB1[r], mfma16(A1f[t][0], XB0[r], z));
                a2[t][r] = mfma16(A2f[t][1], XB1[r], mfma16(A2f[t][0], XB0[r], z));
            }
        }
        bf16x8 HB0[2], HB1[2], GB0[2], GB1[2];
        #pragma unroll
        for (int r = 0; r < 2; ++r) {
            HB0[r] = pack_frag(a1[0][r], a1[1][r]);
            HB1[r] = pack_frag(a1[2][r], a1[3][r]);
            GB0[r] = pack_frag(a2[0][r], a2[1][r]);
            GB1[r] = pack_frag(a2[2][r], a2[3][r]);
        }

        // ---- phase B: Ha -> r1 (W1b), Hb -> r2 (W2b); frags from LDS ----
        f32x4 b1[2][2], b2[2][2];
        #pragma unroll
        for (int t = 0; t < 2; ++t) {
            bf16x8 g10 = *(const bf16x8*)&lfrag[(24 + t * 2 + 0) * 512 + lane * 8];
            bf16x8 g11 = *(const bf16x8*)&lfrag[(24 + t * 2 + 1) * 512 + lane * 8];
            bf16x8 g20 = *(const bf16x8*)&lfrag[(28 + t * 2 + 0) * 512 + lane * 8];
            bf16x8 g21 = *(const bf16x8*)&lfrag[(28 + t * 2 + 1) * 512 + lane * 8];
            #pragma unroll
            for (int r = 0; r < 2; ++r) {
                f32x4 z = {0.f, 0.f, 0.f, 0.f};
                b1[t][r] = mfma16(g11, HB1[r], mfma16(g10, HB0[r], z));
                b2[t][r] = mfma16(g21, GB1[r], mfma16(g20, GB0[r], z));
            }
        }
        bf16x8 RB0[2], RB1[2];
        #pragma unroll
        for (int r = 0; r < 2; ++r) {
            RB0[r] = pack_frag(b1[0][r], b1[1][r]);   // r1 -> A3 s=0 slots
            RB1[r] = pack_frag(b2[0][r], b2[1][r]);   // r2 -> A3 s=1 slots
        }

        // ---- phase C: h = W3a'*[r1;r2] + xd*w3x + b3a; out = relu(dot(relu(h), w3b) + bb) ----
        float p[2] = {0.f, 0.f};
        #pragma unroll
        for (int t = 0; t < 4; ++t) {
            bf16x8 h0 = *(const bf16x8*)&lfrag[(16 + t * 2 + 0) * 512 + lane * 8];
            bf16x8 h1 = *(const bf16x8*)&lfrag[(16 + t * 2 + 1) * 512 + lane * 8];
            f32x4 bv = *(const f32x4*)&s_vec[0][t][q][0];
            f32x4 xv = *(const f32x4*)&s_vec[1][t][q][0];
            f32x4 wv = *(const f32x4*)&s_vec[2][t][q][0];
            #pragma unroll
            for (int r = 0; r < 2; ++r) {
                f32x4 acc;
                #pragma unroll
                for (int e = 0; e < 4; ++e) acc[e] = fmaf(xd[r], xv[e], bv[e]);
                acc = mfma16(h0, RB0[r], acc);
                acc = mfma16(h1, RB1[r], acc);
                #pragma unroll
                for (int e = 0; e < 4; ++e) p[r] = fmaf(fmaxf(acc[e], 0.f), wv[e], p[r]);
            }
        }
        #pragma unroll
        for (int r = 0; r < 2; ++r) {
            float pp = p[r];
            pp += __shfl_xor(pp, 16);
            pp += __shfl_xor(pp, 32);
            int rw = wbase + (k << 5) + (r << 4) + c0;
            if (lane < 16) out[(rw << 6) + i] = fmaxf(pp + bb, 0.f);
        }

        #pragma unroll
        for (int r = 0; r < 2; ++r) { XB0[r] = nXB0[r]; XB1[r] = nXB1[r]; xd[r] = nxd[r]; }
    }
}

extern "C" void kernel_launch(void* const* d_in, const int* in_sizes, int n_in,
                              void* d_out, int out_size, void* d_ws, size_t ws_size,
                              hipStream_t stream) {
    (void)in_sizes; (void)n_in; (void)out_size; (void)ws_size;
    const float* x   = (const float*)d_in[0];
    const float* W1a = (const float*)d_in[1];
    const float* W1b = (const float*)d_in[2];
    const float* W2a = (const float*)d_in[3];
    const float* W2b = (const float*)d_in[4];
    const float* W3a = (const float*)d_in[5];
    const float* b3a = (const float*)d_in[6];
    const float* W3b = (const float*)d_in[7];
    const float* b3b = (const float*)d_in[8];
    float* out = (float*)d_out;
    unsigned short* xb = (unsigned short*)d_ws;

    prep_x<<<512, 256, 0, stream>>>(x, xb);
    main_kernel<<<512, 256, 0, stream>>>(x, W1a, W1b, W2a, W2b, W3a, b3a, W3b, b3b, xb, out);
}

// Round 11
// 115.968 us; speedup vs baseline: 2.6756x; 1.0320x over previous
//
#include <hip/hip_runtime.h>

// N=64 nodes, H=64, M=32, B=16384.
// R8 base: LDS weight fragments, cvt_pk pack (55.4us). VGPR fell to 84 ->
// hoists sunk. ROOT CAUSE identified: AMDGPU RA budget = 512 / (waves/SIMD
// implied by LDS size). LDS 33.8KB -> 4 blocks/CU -> 4 waves/SIMD -> budget
// 128 (R4 compiled to exactly 128; R8 demand ~148 > 128 -> hoists sunk).
// R9: pad LDS to ~54.8KB -> 2 blocks/CU -> 2 waves/SIMD -> budget 256.
// Runtime cost zero (grid 512 = 2 blocks/CU anyway, and R7 proved more
// blocks don't help). Now the source hoists (A1/A2 frags, 64 VGPRs; phase-C
// f32 vectors, 48 VGPRs) fit: in-loop LDS reads drop 44 -> 16 per chunk.
// Fallback if compiler still sinks: identical to R8 (55us), no downside.

typedef short bf16x8 __attribute__((ext_vector_type(8)));
typedef float f32x4  __attribute__((ext_vector_type(4)));
typedef unsigned int u32x4 __attribute__((ext_vector_type(4)));

__device__ __forceinline__ unsigned int pack2(float a, float b) {
    // f32x2 -> packed bf16x2 in ONE VALU op (RTNE); a -> low16, b -> high16
    unsigned int r;
    asm("v_cvt_pk_bf16_f32 %0, %1, %2" : "=v"(r) : "v"(a), "v"(b));
    return r;
}

__device__ __forceinline__ f32x4 mfma16(bf16x8 a, bf16x8 b, f32x4 c) {
    return __builtin_amdgcn_mfma_f32_16x16x32_bf16(a, b, c, 0, 0, 0);
}

// pack two relu'd f32x4 D-blocks into one bf16x8 B-operand fragment
__device__ __forceinline__ bf16x8 pack_frag(f32x4 lo, f32x4 hi) {
    union { u32x4 u; bf16x8 v; } r;
    r.u[0] = pack2(fmaxf(lo[0], 0.f), fmaxf(lo[1], 0.f));
    r.u[1] = pack2(fmaxf(lo[2], 0.f), fmaxf(lo[3], 0.f));
    r.u[2] = pack2(fmaxf(hi[0], 0.f), fmaxf(hi[1], 0.f));
    r.u[3] = pack2(fmaxf(hi[2], 0.f), fmaxf(hi[3], 0.f));
    return r.v;
}

// convert 2x f32x4 (possibly non-adjacent) into a bf16x8 A-fragment
__device__ __forceinline__ bf16x8 cvt_frag2(const float* __restrict__ plo,
                                            const float* __restrict__ phi) {
    f32x4 f0 = *(const f32x4*)plo;
    f32x4 f1 = *(const f32x4*)phi;
    union { u32x4 u; bf16x8 v; } r;
    r.u[0] = pack2(f0[0], f0[1]);
    r.u[1] = pack2(f0[2], f0[3]);
    r.u[2] = pack2(f1[0], f1[1]);
    r.u[3] = pack2(f1[2], f1[3]);
    return r.v;
}

__device__ __forceinline__ bf16x8 cvt_frag2_m(const float* __restrict__ plo,
                                              const float* __restrict__ phi,
                                              const unsigned int* M) {
    f32x4 f0 = *(const f32x4*)plo;
    f32x4 f1 = *(const f32x4*)phi;
    union { u32x4 u; bf16x8 v; } r;
    r.u[0] = pack2(f0[0], f0[1]) & M[0];
    r.u[1] = pack2(f0[2], f0[3]) & M[1];
    r.u[2] = pack2(f1[0], f1[1]) & M[2];
    r.u[3] = pack2(f1[2], f1[3]) & M[3];
    return r.v;
}

__global__ __launch_bounds__(256) void prep_x(const float* __restrict__ x,
                                              unsigned short* __restrict__ xb) {
    int j = (blockIdx.x * 256 + threadIdx.x) * 8;
    f32x4 a = *(const f32x4*)&x[j];
    f32x4 b = *(const f32x4*)&x[j + 4];
    u32x4 r = { pack2(a[0], a[1]), pack2(a[2], a[3]), pack2(b[0], b[1]), pack2(b[2], b[3]) };
    *(u32x4*)&xb[j] = r;
}

__global__ __launch_bounds__(256, 2) void main_kernel(
    const float* __restrict__ x,
    const float* __restrict__ W1a, const float* __restrict__ W1b,
    const float* __restrict__ W2a, const float* __restrict__ W2b,
    const float* __restrict__ W3a, const float* __restrict__ b3a,
    const float* __restrict__ W3b, const float* __restrict__ b3b,
    const unsigned short* __restrict__ xb,
    float* __restrict__ out)
{
    const int i    = blockIdx.x & 63;   // same-i blocks 64-strided -> same XCD (weight L2 locality)
    const int bg   = blockIdx.x >> 6;   // 0..7
    const int tid  = threadIdx.x;
    const int w    = tid >> 6;
    const int lane = tid & 63;
    const int q    = lane >> 4;
    const int c0   = lane & 15;

    // 32 fragments x 64 lanes x 16B (first 32KB) + 22KB pad.
    // The pad drops LDS-implied occupancy to 2 blocks/CU, raising the RA
    // VGPR budget from 128 to 256 so the register hoists below materialize.
    __shared__ short lfrag[32 * 512 + 11264];
    __shared__ float s_vec[3][4][4][4];   // [b3a|w3x|w3b][t][q][r]

    // masks zeroing weight input-column i of W1a/W2a (== masking x column i)
    unsigned int M[2][4];
    {
        const unsigned int halfmask = (i & 1) ? 0x0000FFFFu : 0xFFFF0000u;
        const int dz = (i >> 1) & 3;
        #pragma unroll
        for (int s = 0; s < 2; ++s) {
            bool hit = ((i >> 3) == s * 4 + q);
            #pragma unroll
            for (int d = 0; d < 4; ++d)
                M[s][d] = (hit && d == dz) ? halfmask : 0xFFFFFFFFu;
        }
    }

    // ---- prologue: build all fragments in LDS (each wave owns 8 frag slots) ----
    if (w == 0) {
        const float* p1 = W1a + (i << 12);
        #pragma unroll
        for (int j = 0; j < 8; ++j) {
            int t = j >> 1, s = j & 1;
            int off = (((t << 4) + c0) << 6) + (s << 5) + (q << 3);
            bf16x8 fr = cvt_frag2_m(p1 + off, p1 + off + 4, M[s]);
            *(bf16x8*)&lfrag[j * 512 + lane * 8] = fr;
        }
    } else if (w == 1) {
        const float* p2 = W2a + (i << 12);
        #pragma unroll
        for (int j = 0; j < 8; ++j) {
            int t = j >> 1, s = j & 1;
            int off = (((t << 4) + c0) << 6) + (s << 5) + (q << 3);
            bf16x8 fr = cvt_frag2_m(p2 + off, p2 + off + 4, M[s]);
            *(bf16x8*)&lfrag[(8 + j) * 512 + lane * 8] = fr;
        }
    } else if (w == 2) {
        const float* p3 = W3a + (i << 13);
        #pragma unroll
        for (int j = 0; j < 8; ++j) {
            int t = j >> 1, s = j & 1;
            int base = (((t << 4) + c0) << 7) + (s << 5) + (q << 2);
            bf16x8 fr = cvt_frag2(p3 + base, p3 + base + 16);
            *(bf16x8*)&lfrag[(16 + j) * 512 + lane * 8] = fr;
        }
    } else {
        const float* pb1 = W1b + (i << 11);
        const float* pb2 = W2b + (i << 11);
        #pragma unroll
        for (int j = 0; j < 4; ++j) {
            int t = j >> 1, s = j & 1;
            int base = (((t << 4) + c0) << 6) + (s << 5) + (q << 2);
            bf16x8 fr1 = cvt_frag2(pb1 + base, pb1 + base + 16);
            bf16x8 fr2 = cvt_frag2(pb2 + base, pb2 + base + 16);
            *(bf16x8*)&lfrag[(24 + j) * 512 + lane * 8] = fr1;
            *(bf16x8*)&lfrag[(28 + j) * 512 + lane * 8] = fr2;
        }
    }
    if (tid < 64) {
        int tt = tid >> 4, qq = (tid >> 2) & 3, rr = tid & 3;
        s_vec[0][tt][qq][rr] = b3a[(i << 6) + tid];
        s_vec[2][tt][qq][rr] = W3b[(i << 6) + tid];
        s_vec[1][tt][qq][rr] = W3a[(i << 13) + (tid << 7) + 64 + i];
    }
    const float bb = b3b[i];
    __syncthreads();

    // ---- register hoists (now affordable under the 256-VGPR budget) ----
    // phase-A fragments: 16 frags = 64 VGPRs
    bf16x8 A1f[4][2], A2f[4][2];
    #pragma unroll
    for (int t = 0; t < 4; ++t)
        #pragma unroll
        for (int s = 0; s < 2; ++s) {
            A1f[t][s] = *(const bf16x8*)&lfrag[(t * 2 + s) * 512 + lane * 8];
            A2f[t][s] = *(const bf16x8*)&lfrag[(8 + t * 2 + s) * 512 + lane * 8];
        }
    // phase-C f32 vectors: 12 f32x4 = 48 VGPRs
    f32x4 b3av[4], w3xv[4], w3bv[4];
    #pragma unroll
    for (int t = 0; t < 4; ++t) {
        b3av[t] = *(const f32x4*)&s_vec[0][t][q][0];
        w3xv[t] = *(const f32x4*)&s_vec[1][t][q][0];
        w3bv[t] = *(const f32x4*)&s_vec[2][t][q][0];
    }

    const int wbase = (((bg << 2) + w) << 9);  // 512 rows per wave, 16 chunks of 32

    // preload chunk 0 (2 subtiles of 16 rows)
    bf16x8 XB0[2], XB1[2]; float xd[2];
    #pragma unroll
    for (int r = 0; r < 2; ++r) {
        int rw = wbase + (r << 4) + c0;
        XB0[r] = *(const bf16x8*)&xb[(rw << 6) + (q << 3)];
        XB1[r] = *(const bf16x8*)&xb[(rw << 6) + 32 + (q << 3)];
        xd[r]  = x[(rw << 6) + i];
    }

    for (int k = 0; k < 16; ++k) {
        // prefetch next chunk
        int nb = wbase + ((k < 15 ? k + 1 : 15) << 5) + c0;
        bf16x8 nXB0[2], nXB1[2]; float nxd[2];
        #pragma unroll
        for (int r = 0; r < 2; ++r) {
            int rw = nb + (r << 4);
            nXB0[r] = *(const bf16x8*)&xb[(rw << 6) + (q << 3)];
            nXB1[r] = *(const bf16x8*)&xb[(rw << 6) + 32 + (q << 3)];
            nxd[r]  = x[(rw << 6) + i];
        }

        // ---- phase A: x -> Ha (W1a), x -> Hb (W2a); frags from registers ----
        f32x4 a1[4][2], a2[4][2];
        #pragma unroll
        for (int t = 0; t < 4; ++t) {
            #pragma unroll
            for (int r = 0; r < 2; ++r) {
                f32x4 z = {0.f, 0.f, 0.f, 0.f};
                a1[t][r] = mfma16(A1f[t][1], XB1[r], mfma16(A1f[t][0], XB0[r], z));
                a2[t][r] = mfma16(A2f[t][1], XB1[r], mfma16(A2f[t][0], XB0[r], z));
            }
        }
        bf16x8 HB0[2], HB1[2], GB0[2], GB1[2];
        #pragma unroll
        for (int r = 0; r < 2; ++r) {
            HB0[r] = pack_frag(a1[0][r], a1[1][r]);
            HB1[r] = pack_frag(a1[2][r], a1[3][r]);
            GB0[r] = pack_frag(a2[0][r], a2[1][r]);
            GB1[r] = pack_frag(a2[2][r], a2[3][r]);
        }

        // ---- phase B: Ha -> r1 (W1b), Hb -> r2 (W2b); frags from LDS ----
        f32x4 b1[2][2], b2[2][2];
        #pragma unroll
        for (int t = 0; t < 2; ++t) {
            bf16x8 g10 = *(const bf16x8*)&lfrag[(24 + t * 2 + 0) * 512 + lane * 8];
            bf16x8 g11 = *(const bf16x8*)&lfrag[(24 + t * 2 + 1) * 512 + lane * 8];
            bf16x8 g20 = *(const bf16x8*)&lfrag[(28 + t * 2 + 0) * 512 + lane * 8];
            bf16x8 g21 = *(const bf16x8*)&lfrag[(28 + t * 2 + 1) * 512 + lane * 8];
            #pragma unroll
            for (int r = 0; r < 2; ++r) {
                f32x4 z = {0.f, 0.f, 0.f, 0.f};
                b1[t][r] = mfma16(g11, HB1[r], mfma16(g10, HB0[r], z));
                b2[t][r] = mfma16(g21, GB1[r], mfma16(g20, GB0[r], z));
            }
        }
        bf16x8 RB0[2], RB1[2];
        #pragma unroll
        for (int r = 0; r < 2; ++r) {
            RB0[r] = pack_frag(b1[0][r], b1[1][r]);   // r1 -> A3 s=0 slots
            RB1[r] = pack_frag(b2[0][r], b2[1][r]);   // r2 -> A3 s=1 slots
        }

        // ---- phase C: h = W3a'*[r1;r2] + xd*w3x + b3a; out = relu(dot(relu(h), w3b) + bb) ----
        float p[2] = {0.f, 0.f};
        #pragma unroll
        for (int t = 0; t < 4; ++t) {
            bf16x8 h0 = *(const bf16x8*)&lfrag[(16 + t * 2 + 0) * 512 + lane * 8];
            bf16x8 h1 = *(const bf16x8*)&lfrag[(16 + t * 2 + 1) * 512 + lane * 8];
            #pragma unroll
            for (int r = 0; r < 2; ++r) {
                f32x4 acc;
                #pragma unroll
                for (int e = 0; e < 4; ++e) acc[e] = fmaf(xd[r], w3xv[t][e], b3av[t][e]);
                acc = mfma16(h0, RB0[r], acc);
                acc = mfma16(h1, RB1[r], acc);
                #pragma unroll
                for (int e = 0; e < 4; ++e) p[r] = fmaf(fmaxf(acc[e], 0.f), w3bv[t][e], p[r]);
            }
        }
        #pragma unroll
        for (int r = 0; r < 2; ++r) {
            float pp = p[r];
            pp += __shfl_xor(pp, 16);
            pp += __shfl_xor(pp, 32);
            int rw = wbase + (k << 5) + (r << 4) + c0;
            if (lane < 16) out[(rw << 6) + i] = fmaxf(pp + bb, 0.f);
        }

        #pragma unroll
        for (int r = 0; r < 2; ++r) { XB0[r] = nXB0[r]; XB1[r] = nXB1[r]; xd[r] = nxd[r]; }
    }
}

extern "C" void kernel_launch(void* const* d_in, const int* in_sizes, int n_in,
                              void* d_out, int out_size, void* d_ws, size_t ws_size,
                              hipStream_t stream) {
    (void)in_sizes; (void)n_in; (void)out_size; (void)ws_size;
    const float* x   = (const float*)d_in[0];
    const float* W1a = (const float*)d_in[1];
    const float* W1b = (const float*)d_in[2];
    const float* W2a = (const float*)d_in[3];
    const float* W2b = (const float*)d_in[4];
    const float* W3a = (const float*)d_in[5];
    const float* b3a = (const float*)d_in[6];
    const float* W3b = (const float*)d_in[7];
    const float* b3b = (const float*)d_in[8];
    float* out = (float*)d_out;
    unsigned short* xb = (unsigned short*)d_ws;

    prep_x<<<512, 256, 0, stream>>>(x, xb);
    main_kernel<<<512, 256, 0, stream>>>(x, W1a, W1b, W2a, W2b, W3a, b3a, W3b, b3b, xb, out);
}